// Round 18
// baseline (462.881 us; speedup 1.0000x reference)
//
#include <hip/hip_runtime.h>
#include <cstdint>
#include <cstddef>

constexpr int Hd  = 256;
constexpr int N_P = 100000;
constexpr int N_A = 20000;
constexpr int F_P = 512;
constexpr int D_A = 128;

typedef short bf16x8 __attribute__((ext_vector_type(8)));
typedef float f32x4  __attribute__((ext_vector_type(4)));

__device__ __forceinline__ unsigned short f2b(float x) {
    unsigned u = __float_as_uint(x);
    u += 0x7fffu + ((u >> 16) & 1u);
    return (unsigned short)(u >> 16);
}
__device__ __forceinline__ float b2f(unsigned short h) {
    return __uint_as_float((unsigned)h << 16);
}
__device__ __forceinline__ unsigned pk2(float lo, float hi) {
    return (__float_as_uint(lo) >> 16) | (__float_as_uint(hi) & 0xffff0000u);
}
__device__ __forceinline__ void bsplit(float x, unsigned short& hi, unsigned short& lo) {
    const unsigned u = __float_as_uint(x);
    hi = (unsigned short)(u >> 16);
    const float r = x - __uint_as_float(u & 0xffff0000u);
    lo = (unsigned short)(__float_as_uint(r) >> 16);
}

// async global->LDS, 16B per lane (m173 pre-swizzled-source pattern).
__device__ __forceinline__ void gld16(const void* g, void* l) {
    __builtin_amdgcn_global_load_lds(
        (const __attribute__((address_space(1))) unsigned int*)g,
        (__attribute__((address_space(3))) unsigned int*)l, 16, 0, 0);
}

// ---------------------------------------------------------------------------
// prep: pack W tables into MFMA B-fragment layout + bias concats. (proven)
// ---------------------------------------------------------------------------
__global__ void prep_kernel(const float* __restrict__ W1sa, const float* __restrict__ W1rw,
                            const float* __restrict__ W2sa, const float* __restrict__ W2rw,
                            const float* __restrict__ W2rc, const float* __restrict__ W2sp,
                            const float* __restrict__ W1sp, const float* __restrict__ W1rc,
                            const float* __restrict__ b1sa, const float* __restrict__ b1rw,
                            const float* __restrict__ b2sa, const float* __restrict__ b2rw,
                            const float* __restrict__ b2rc, const float* __restrict__ b2sp,
                            const float* __restrict__ b1sp, const float* __restrict__ b1rc,
                            unsigned short* __restrict__ w1h,  unsigned short* __restrict__ w1l,
                            unsigned short* __restrict__ wA2h, unsigned short* __restrict__ wA2l,
                            unsigned short* __restrict__ wP2h,
                            unsigned short* __restrict__ wP1h,
                            float* __restrict__ bc1, float* __restrict__ bcA2,
                            float* __restrict__ bcP2, float* __restrict__ bcP1) {
    const int b = blockIdx.x;
    const int l = threadIdx.x;
    if (b < 384) {
        const float *Wa, *Wb; unsigned short *wh, *wl; int rel;
        if (b < 128) { Wa = W1sa; Wb = W1rw; wh = w1h;  wl = w1l;  rel = b; }
        else         { Wa = W2sa; Wb = W2rw; wh = wA2h; wl = wA2l; rel = b - 128; }
        const int ks  = rel >> 5;
        const int nfg = rel & 31;
        const float* W = (nfg < 16) ? Wa : Wb;
        const int col  = (nfg & 15) * 16 + (l & 15);
        const size_t base = ((size_t)rel * 64 + l) * 8;
        #pragma unroll
        for (int j = 0; j < 8; ++j) {
            const int k = ks * 32 + ((l >> 4) * 8) + j;
            unsigned short h, lw;
            bsplit(W[(size_t)k * Hd + col], h, lw);
            wh[base + j] = h;
            wl[base + j] = lw;
        }
    } else if (b < 640) {
        const int rel = b - 384;                  // [0,256)
        const int ks  = rel >> 5;
        const int nfg = rel & 31;
        const float* W = (nfg < 16) ? W2rc : W2sp;
        const int col  = (nfg & 15) * 16 + (l & 15);
        const size_t base = ((size_t)rel * 64 + l) * 8;
        #pragma unroll
        for (int j = 0; j < 8; ++j) {
            const int k = ks * 32 + ((l >> 4) * 8) + j;
            wP2h[base + j] = f2b(W[(size_t)k * Hd + col]);
        }
    } else if (b < 1152) {
        const int rel = b - 640;                  // [0,512)
        const int ks  = rel >> 5;
        const int nfg = rel & 31;
        const float* W = (nfg < 16) ? W1sp : W1rc;
        const int col  = (nfg & 15) * 16 + (l & 15);
        const size_t base = ((size_t)rel * 64 + l) * 8;
        #pragma unroll
        for (int j = 0; j < 8; ++j) {
            const int k = ks * 32 + ((l >> 4) * 8) + j;
            wP1h[base + j] = f2b(W[(size_t)k * Hd + col]);
        }
    } else {
        const int t     = (b - 1152) * 64 + l;    // 0..2047
        const int which = t >> 9;
        const int idx   = t & 511;
        const float* src; float* dst;
        if (which == 0)      { src = (idx < 256) ? b1sa : b1rw; dst = bc1;  }
        else if (which == 1) { src = (idx < 256) ? b2sa : b2rw; dst = bcA2; }
        else if (which == 2) { src = (idx < 256) ? b2rc : b2sp; dst = bcP2; }
        else                 { src = (idx < 256) ? b1sp : b1rc; dst = bcP1; }
        dst[idx] = src[idx & 255];
    }
}

// ---------------------------------------------------------------------------
// Fused conv + hist: blocks [0,1024) stream pf fp32->bf16 (HBM-bound);
// blocks [1024,2048) histogram edge dsts (latency-bound) -- the atomic
// latency hides under the conv's HBM streaming.
// ---------------------------------------------------------------------------
__global__ void convhist_kernel(const float* __restrict__ in, unsigned short* __restrict__ out,
                                const long n4,
                                const int* __restrict__ wdst, const int EW,
                                const int* __restrict__ cdst, const int EC,
                                int* __restrict__ cnt) {
    const int b = blockIdx.x;
    if (b < 1024) {
        const long stride = (long)1024 * blockDim.x;
        for (long i = (long)b * blockDim.x + threadIdx.x; i < n4; i += stride) {
            const float4 v = ((const float4*)in)[i];
            ((ushort4*)out)[i] = make_ushort4(
                (unsigned short)(__float_as_uint(v.x) >> 16),
                (unsigned short)(__float_as_uint(v.y) >> 16),
                (unsigned short)(__float_as_uint(v.z) >> 16),
                (unsigned short)(__float_as_uint(v.w) >> 16));
        }
    } else {
        const int stride = 1024 * blockDim.x;
        for (int i = (b - 1024) * blockDim.x + threadIdx.x; i < EW + EC; i += stride) {
            const int d = (i < EW) ? wdst[i] : cdst[i - EW];
            atomicAdd(&cnt[d], 1);
        }
    }
}

// standalone hist (fallback path without pfb)
__global__ void hist_kernel(const int* __restrict__ wdst, const int EW,
                            const int* __restrict__ cdst, const int EC,
                            int* __restrict__ cnt) {
    for (int i = blockIdx.x * blockDim.x + threadIdx.x; i < EW + EC; i += gridDim.x * blockDim.x) {
        const int d = (i < EW) ? wdst[i] : cdst[i - EW];
        atomicAdd(&cnt[d], 1);
    }
}

// ---------------------------------------------------------------------------
// TILE2 MFMA GEMM (m97-style): 128x128 tile, BK=32, 4 waves (64x64 each,
// acc[4][4]). B via global_load_lds; AMODE=1: bf16 A via global_load_lds;
// AMODE=0: fp32 A reg-staged (fallback). One barrier per K-step.
// XCD-grouped block mapping (proven R17).
// ---------------------------------------------------------------------------
template<int AMODE>
__global__ void __launch_bounds__(256, 3)
mfma_tile2_kernel(const void* __restrict__ Av, const int KA, const int nks,
                  const unsigned short* __restrict__ wtab,
                  const float* __restrict__ bcat,
                  void* __restrict__ Oa, void* __restrict__ Ob,
                  const int bfA, const int bfB, const int Mtot, const int gM) {
    const int d = blockIdx.x;
    const int r = ((d >> 5) << 3) + (d & 7);
    if (r >= gM) return;
    const int c = (d >> 3) & 3;

    extern __shared__ char smem[];                 // [2][ A:8KB | B:8KB ]
    const int tid = threadIdx.x;
    const int wid = tid >> 6;
    const int l   = tid & 63;
    const long m0 = (long)r * 128;
    const int wr  = wid >> 1, wc = wid & 1;

    const unsigned short* bg0 = wtab + ((size_t)(c * 8 + 2 * wid) * 512) + l * 8;
    const unsigned short* bg1 = bg0 + 512;

    const unsigned short* ag0 = nullptr; const unsigned short* ag1 = nullptr;
    const float* Af = nullptr;
    long grow0 = 0, grow1 = 0; int kg = 0;
    if constexpr (AMODE == 1) {
        const unsigned short* A = (const unsigned short*)Av;
        long r0 = m0 + (2 * wid) * 16 + (l & 15);     if (r0 > Mtot - 1) r0 = Mtot - 1;
        long r1 = m0 + (2 * wid + 1) * 16 + (l & 15); if (r1 > Mtot - 1) r1 = Mtot - 1;
        ag0 = A + r0 * KA + ((l >> 4) * 8);
        ag1 = A + r1 * KA + ((l >> 4) * 8);
    } else {
        Af = (const float*)Av;
        const int f0 = tid >> 6;
        grow0 = m0 + f0 * 16 + (l & 15);       if (grow0 > Mtot - 1) grow0 = Mtot - 1;
        grow1 = m0 + (f0 + 4) * 16 + (l & 15); if (grow1 > Mtot - 1) grow1 = Mtot - 1;
        kg = (l >> 4) * 8;
    }

    float4 a00, a01, a10, a11;

#define STAGE_B(BUF, KS) { \
    char* Bb_ = smem + (BUF) * 16384 + 8192; \
    gld16(bg0 + (size_t)(KS) * 16384, Bb_ + wid * 2048); \
    gld16(bg1 + (size_t)(KS) * 16384, Bb_ + wid * 2048 + 1024); }
#define STAGE_A1(BUF, KS) { \
    char* Ab_ = smem + (BUF) * 16384; \
    gld16(ag0 + (KS) * 32, Ab_ + wid * 2048); \
    gld16(ag1 + (KS) * 32, Ab_ + wid * 2048 + 1024); }
#define LOAD_A0(KS) { \
    const float* p0_ = Af + grow0 * KA + (KS) * 32 + kg; \
    const float* p1_ = Af + grow1 * KA + (KS) * 32 + kg; \
    a00 = *(const float4*)p0_; a01 = *(const float4*)(p0_ + 4); \
    a10 = *(const float4*)p1_; a11 = *(const float4*)(p1_ + 4); }
#define WRITE_A0(BUF) { \
    char* Ab_ = smem + (BUF) * 16384; \
    *(uint4*)(Ab_ + tid * 16) = make_uint4(pk2(a00.x, a00.y), pk2(a00.z, a00.w), \
                                           pk2(a01.x, a01.y), pk2(a01.z, a01.w)); \
    *(uint4*)(Ab_ + (tid + 256) * 16) = make_uint4(pk2(a10.x, a10.y), pk2(a10.z, a10.w), \
                                                   pk2(a11.x, a11.y), pk2(a11.z, a11.w)); }

    f32x4 acc[4][4];
    #pragma unroll
    for (int nf = 0; nf < 4; ++nf) {
        const float b = bcat[c * 128 + wc * 64 + nf * 16 + (l & 15)];
        #pragma unroll
        for (int mf = 0; mf < 4; ++mf) acc[mf][nf] = (f32x4){b, b, b, b};
    }

    STAGE_B(0, 0)
    if constexpr (AMODE == 1) { STAGE_A1(0, 0) }
    else { LOAD_A0(0) WRITE_A0(0) }
    __syncthreads();

    int cur = 0;
    for (int ks = 0; ks < nks; ++ks) {
        const bool more = (ks + 1 < nks);
        if (more) {
            STAGE_B(cur ^ 1, ks + 1)
            if constexpr (AMODE == 1) { STAGE_A1(cur ^ 1, ks + 1) }
            else { LOAD_A0(ks + 1) }
        }
        {
            const char* Ab = smem + cur * 16384;
            const char* Bb = Ab + 8192;
            bf16x8 af[4], bfv[4];
            #pragma unroll
            for (int mf = 0; mf < 4; ++mf)
                af[mf] = *(const bf16x8*)(Ab + ((wr * 4 + mf) * 64 + l) * 16);
            #pragma unroll
            for (int nf = 0; nf < 4; ++nf)
                bfv[nf] = *(const bf16x8*)(Bb + ((wc * 4 + nf) * 64 + l) * 16);
            #pragma unroll
            for (int nf = 0; nf < 4; ++nf) {
                #pragma unroll
                for (int mf = 0; mf < 4; ++mf)
                    acc[mf][nf] = __builtin_amdgcn_mfma_f32_16x16x32_bf16(af[mf], bfv[nf], acc[mf][nf], 0, 0, 0);
            }
        }
        if (more) { if constexpr (AMODE == 0) WRITE_A0(cur ^ 1) }
        __syncthreads();
        cur ^= 1;
    }
#undef STAGE_B
#undef STAGE_A1
#undef LOAD_A0
#undef WRITE_A0

    #pragma unroll
    for (int mf = 0; mf < 4; ++mf) {
        #pragma unroll
        for (int nf = 0; nf < 4; ++nf) {
            const int gcol = c * 128 + wc * 64 + nf * 16 + (l & 15);
            void* O; int col, isbf;
            if (gcol < 256) { O = Oa; col = gcol;       isbf = bfA; }
            else            { O = Ob; col = gcol - 256; isbf = bfB; }
            const long row = m0 + wr * 64 + mf * 16 + ((l >> 4) * 4);
            const f32x4 v = acc[mf][nf];
            #pragma unroll
            for (int rr = 0; rr < 4; ++rr) {
                if (row + rr < Mtot) {
                    const float x = v[rr];
                    if (isbf) ((unsigned short*)O)[(row + rr) * Hd + col] = f2b(x);
                    else      ((float*)O)[(row + rr) * Hd + col] = x;
                }
            }
        }
    }
}

// ---------------------------------------------------------------------------
// Dual-output MFMA GEMM (author GEMMs only): fp32 A, split-bf16 3-product.
// ---------------------------------------------------------------------------
__global__ void mfma_dual_kernel(const void* __restrict__ Av, const int K,
                                 const unsigned short* __restrict__ whi,
                                 const unsigned short* __restrict__ wlo,
                                 const float* __restrict__ bcat,
                                 void* __restrict__ Oa, void* __restrict__ Ob,
                                 const int actA, const int actB,
                                 const int bfA, const int bfB) {
    extern __shared__ char smem[];
    char* sh = smem;
    char* sl = smem + 32 * K * 2;
    const int  tid = threadIdx.x;
    const int  wid = tid >> 6;
    const int  l   = tid & 63;
    const long m0  = (long)blockIdx.x * 32;
    const int  rowStride = 2 * K;

    const int kq4 = K >> 2;
    const float* A = (const float*)Av;
    for (int i = tid; i < 32 * kq4; i += 256) {
        const int row = i / kq4;
        const int kq  = i - row * kq4;
        const float4 v = *(const float4*)(A + (m0 + row) * K + kq * 4);
        unsigned short h0, h1, h2, h3, l0, l1, l2, l3;
        bsplit(v.x, h0, l0); bsplit(v.y, h1, l1);
        bsplit(v.z, h2, l2); bsplit(v.w, h3, l3);
        const int ofs = row * rowStride + ((kq * 8) ^ ((row & 7) << 4));
        *(ushort4*)(sh + ofs) = make_ushort4(h0, h1, h2, h3);
        *(ushort4*)(sl + ofs) = make_ushort4(l0, l1, l2, l3);
    }
    __syncthreads();

    f32x4 acc[2][8];
    #pragma unroll
    for (int nf = 0; nf < 8; ++nf) {
        const float b = bcat[wid * 128 + nf * 16 + (l & 15)];
        acc[0][nf] = (f32x4){b, b, b, b};
        acc[1][nf] = (f32x4){b, b, b, b};
    }

    const int kb  = (l >> 4) * 16;
    const int r0  = l & 15;
    const int r1  = 16 + r0;
    const int sw  = (l & 7) << 4;
    const int ro0 = r0 * rowStride;
    const int ro1 = r1 * rowStride;
    for (int ks = 0; ks < (K >> 5); ++ks) {
        const int bk = (ks * 64 + kb) ^ sw;
        const bf16x8 ah0 = *(const bf16x8*)(sh + ro0 + bk);
        const bf16x8 ah1 = *(const bf16x8*)(sh + ro1 + bk);
        const bf16x8 al0 = *(const bf16x8*)(sl + ro0 + bk);
        const bf16x8 al1 = *(const bf16x8*)(sl + ro1 + bk);
        const size_t wbase = (((size_t)ks * 32 + wid * 8) * 64 + l) * 8;
        #pragma unroll
        for (int nf = 0; nf < 8; ++nf) {
            const bf16x8 bh = *(const bf16x8*)(whi + wbase + (size_t)nf * 512);
            const bf16x8 bl = *(const bf16x8*)(wlo + wbase + (size_t)nf * 512);
            acc[0][nf] = __builtin_amdgcn_mfma_f32_16x16x32_bf16(ah0, bh, acc[0][nf], 0, 0, 0);
            acc[1][nf] = __builtin_amdgcn_mfma_f32_16x16x32_bf16(ah1, bh, acc[1][nf], 0, 0, 0);
            acc[0][nf] = __builtin_amdgcn_mfma_f32_16x16x32_bf16(al0, bh, acc[0][nf], 0, 0, 0);
            acc[1][nf] = __builtin_amdgcn_mfma_f32_16x16x32_bf16(al1, bh, acc[1][nf], 0, 0, 0);
            acc[0][nf] = __builtin_amdgcn_mfma_f32_16x16x32_bf16(ah0, bl, acc[0][nf], 0, 0, 0);
            acc[1][nf] = __builtin_amdgcn_mfma_f32_16x16x32_bf16(ah1, bl, acc[1][nf], 0, 0, 0);
        }
    }

    #pragma unroll
    for (int mf = 0; mf < 2; ++mf) {
        #pragma unroll
        for (int nf = 0; nf < 8; ++nf) {
            const int colg = wid * 128 + nf * 16 + (l & 15);
            void* O;
            int col, act, isbf;
            if (colg < 256) { O = Oa; col = colg;       act = actA; isbf = bfA; }
            else            { O = Ob; col = colg - 256; act = actB; isbf = bfB; }
            const long row = m0 + mf * 16 + ((l >> 4) * 4);
            const f32x4 v = acc[mf][nf];
            #pragma unroll
            for (int r = 0; r < 4; ++r) {
                float x = v[r];
                if (act) x = x > 0.f ? x : expm1f(x);
                if (isbf) ((unsigned short*)O)[(row + r) * Hd + col] = f2b(x);
                else      ((float*)O)[(row + r) * Hd + col] = x;
            }
        }
    }
}

// ---------------------------------------------------------------------------
// CSR scans + fill. (proven)
// ---------------------------------------------------------------------------
__global__ void scan1_kernel(int* __restrict__ data, const int n, int* __restrict__ bsum) {
    __shared__ int s[256];
    const int t = threadIdx.x;
    const int base = blockIdx.x * 1024 + t * 4;
    int v0 = (base + 0 < n) ? data[base + 0] : 0;
    int v1 = (base + 1 < n) ? data[base + 1] : 0;
    int v2 = (base + 2 < n) ? data[base + 2] : 0;
    int v3 = (base + 3 < n) ? data[base + 3] : 0;
    const int tsum = v0 + v1 + v2 + v3;
    s[t] = tsum;
    __syncthreads();
    for (int off = 1; off < 256; off <<= 1) {
        int y = (t >= off) ? s[t - off] : 0;
        __syncthreads();
        if (t >= off) s[t] += y;
        __syncthreads();
    }
    const int e = s[t] - tsum;
    if (base + 0 < n) data[base + 0] = e;
    if (base + 1 < n) data[base + 1] = e + v0;
    if (base + 2 < n) data[base + 2] = e + v0 + v1;
    if (base + 3 < n) data[base + 3] = e + v0 + v1 + v2;
    if (t == 255) bsum[blockIdx.x] = s[255];
}

__global__ void scan2_kernel(int* __restrict__ bsum, const int nb) {
    __shared__ int s[256];
    const int t = threadIdx.x;
    const int v = (t < nb) ? bsum[t] : 0;
    s[t] = v;
    __syncthreads();
    for (int off = 1; off < 256; off <<= 1) {
        int y = (t >= off) ? s[t - off] : 0;
        __syncthreads();
        if (t >= off) s[t] += y;
        __syncthreads();
    }
    if (t < nb) bsum[t] = s[t] - v;
}

__global__ void scan3_kernel(int* __restrict__ data, const int n, const int* __restrict__ bsum) {
    const int i = blockIdx.x * blockDim.x + threadIdx.x;
    if (i < n) data[i] += bsum[i >> 10];
}

__global__ void fill_kernel(const int* __restrict__ wsrc, const int* __restrict__ wdst,
                            const float* __restrict__ ww, const int EW,
                            const int* __restrict__ csrc, const int* __restrict__ cdst,
                            const float* __restrict__ cw, const int EC,
                            int* __restrict__ cur, int2* __restrict__ edges) {
    for (int i = blockIdx.x * blockDim.x + threadIdx.x; i < EW + EC; i += gridDim.x * blockDim.x) {
        int d, sp; float w;
        if (i < EW) { d = wdst[i]; sp = wsrc[i]; w = ww[i]; }
        else        { const int j = i - EW; d = cdst[j]; sp = N_A + csrc[j]; w = cw[j]; }
        const int p = atomicAdd(&cur[d], 1);
        edges[p] = make_int2(sp, __float_as_int(w));
    }
}

// ---------------------------------------------------------------------------
// Pull aggregation: proven skeleton, depth-3 pipeline (12 outstanding
// gathers/wave). MODE 0: fp32 in-place. MODE 1: bf16 in-place (+ELU).
// MODE 2: read bf16 self from iov, write fp32 to outv.
// ---------------------------------------------------------------------------
struct AgChunk { ushort4 g0, g1, g2, g3; float w0, w1, w2, w3; };

__device__ __forceinline__ void ag_issue(const int2* __restrict__ eq, const int base, const int n,
                                         const unsigned short* __restrict__ msg,
                                         const int lane, AgChunk& C) {
#define AG_ONE(J, GG, WW) { \
    const int idx = base + (J); \
    const int2 ee = eq[min(idx, n - 1)]; \
    WW = (idx < n) ? __int_as_float(ee.y) : 0.f; \
    GG = ((const ushort4*)(msg + (size_t)ee.x * Hd))[lane]; }
    AG_ONE(0, C.g0, C.w0)
    AG_ONE(1, C.g1, C.w1)
    AG_ONE(2, C.g2, C.w2)
    AG_ONE(3, C.g3, C.w3)
#undef AG_ONE
}

__device__ __forceinline__ void ag_acc(const AgChunk& C, float4& acc) {
#define AG_A(GG, WW) { \
    acc.x = fmaf(WW, b2f(GG.x), acc.x); acc.y = fmaf(WW, b2f(GG.y), acc.y); \
    acc.z = fmaf(WW, b2f(GG.z), acc.z); acc.w = fmaf(WW, b2f(GG.w), acc.w); }
    AG_A(C.g0, C.w0) AG_A(C.g1, C.w1) AG_A(C.g2, C.w2) AG_A(C.g3, C.w3)
#undef AG_A
}

template<int MODE>
__global__ void aggregate_kernel(void* __restrict__ iov, void* __restrict__ outv,
                                 const unsigned short* __restrict__ msgAll,
                                 const int* __restrict__ off,
                                 const int2* __restrict__ edges,
                                 const int do_elu) {
    __shared__ int2 eq[1024];
    const int wid  = threadIdx.x >> 6;
    const int lane = threadIdx.x & 63;
    const int p0   = blockIdx.x * 4;
    const int sAll = (p0 == 0) ? 0 : off[p0 - 1];
    const int tot  = off[p0 + 3] - sAll;
    const bool fits = (tot <= 1024);
    if (fits)
        for (int i = threadIdx.x; i < tot; i += 256) eq[i] = edges[sAll + i];
    __syncthreads();

    const int p = p0 + wid;
    const int s = (p == 0) ? 0 : off[p - 1];
    const int e = off[p];
    const int n = e - s;

    float4 acc;
    if constexpr (MODE >= 1) {
        const ushort4 t = ((const ushort4*)((const unsigned short*)iov + (size_t)p * Hd))[lane];
        acc = make_float4(b2f(t.x), b2f(t.y), b2f(t.z), b2f(t.w));
    } else {
        acc = ((const float4*)((const float*)iov + (size_t)p * Hd))[lane];
    }

    if (n > 0) {
        if (fits) {
            const int2* eqw = eq + (s - sAll);
            int nc = (n + 3) >> 2;                 // chunks of 4 edges
            nc = ((nc + 2) / 3) * 3;               // multiple of 3, >= 3
            AgChunk CA, CB, CC;
            ag_issue(eqw, 0, n, msgAll, lane, CA);
            ag_issue(eqw, 4, n, msgAll, lane, CB);
            ag_issue(eqw, 8, n, msgAll, lane, CC);
            for (int c = 0; c + 3 < nc; c += 3) {
                ag_acc(CA, acc);
                ag_issue(eqw, 4 * (c + 3), n, msgAll, lane, CA);
                ag_acc(CB, acc);
                ag_issue(eqw, 4 * (c + 4), n, msgAll, lane, CB);
                ag_acc(CC, acc);
                ag_issue(eqw, 4 * (c + 5), n, msgAll, lane, CC);
            }
            ag_acc(CA, acc);
            ag_acc(CB, acc);
            ag_acc(CC, acc);
        } else {
            for (int i = s; i < e; ++i) {
                const int2 ee = edges[i];
                const ushort4 g = ((const ushort4*)(msgAll + (size_t)ee.x * Hd))[lane];
                const float w = __int_as_float(ee.y);
                acc.x = fmaf(w, b2f(g.x), acc.x); acc.y = fmaf(w, b2f(g.y), acc.y);
                acc.z = fmaf(w, b2f(g.z), acc.z); acc.w = fmaf(w, b2f(g.w), acc.w);
            }
        }
    }
    if (do_elu) {
        acc.x = acc.x > 0.f ? acc.x : expm1f(acc.x);
        acc.y = acc.y > 0.f ? acc.y : expm1f(acc.y);
        acc.z = acc.z > 0.f ? acc.z : expm1f(acc.z);
        acc.w = acc.w > 0.f ? acc.w : expm1f(acc.w);
    }
    if constexpr (MODE == 1) {
        ((ushort4*)((unsigned short*)iov + (size_t)p * Hd))[lane] =
            make_ushort4(f2b(acc.x), f2b(acc.y), f2b(acc.z), f2b(acc.w));
    } else if constexpr (MODE == 2) {
        ((float4*)((float*)outv + (size_t)p * Hd))[lane] = acc;
    } else {
        ((float4*)((float*)iov + (size_t)p * Hd))[lane] = acc;
    }
}

extern "C" void kernel_launch(void* const* d_in, const int* in_sizes, int n_in,
                              void* d_out, int out_size, void* d_ws, size_t ws_size,
                              hipStream_t stream) {
    const float* pf    = (const float*)d_in[0];
    const float* ae    = (const float*)d_in[1];
    const int*   wsrc  = (const int*)d_in[2];
    const int*   wdst  = (const int*)d_in[3];
    const float* ww    = (const float*)d_in[4];
    const int*   csrc  = (const int*)d_in[5];
    const int*   cdst  = (const int*)d_in[6];
    const float* cw    = (const float*)d_in[7];
    const float* W1sp  = (const float*)d_in[8];
    const float* b1sp  = (const float*)d_in[9];
    const float* W1sa  = (const float*)d_in[10];
    const float* b1sa  = (const float*)d_in[11];
    const float* W1rw  = (const float*)d_in[12];
    const float* b1rw  = (const float*)d_in[13];
    const float* W1rc  = (const float*)d_in[14];
    const float* b1rc  = (const float*)d_in[15];
    const float* W2sp  = (const float*)d_in[16];
    const float* b2sp  = (const float*)d_in[17];
    const float* W2sa  = (const float*)d_in[18];
    const float* b2sa  = (const float*)d_in[19];
    const float* W2rw  = (const float*)d_in[20];
    const float* b2rw  = (const float*)d_in[21];
    const float* W2rc  = (const float*)d_in[22];
    const float* b2rc  = (const float*)d_in[23];

    const int E_W = in_sizes[2];
    const int E_C = in_sizes[5];

    float* outP = (float*)d_out;                        // [N_P, 256] fp32
    float* outA = outP + (size_t)N_P * Hd;              // [N_A, 256] fp32

    // Workspace layout (R17):
    float*          xa1    = (float*)d_ws;
    unsigned short* xp1b   = (unsigned short*)(xa1 + (size_t)N_A * Hd);
    unsigned short* msgAll = xp1b + (size_t)N_P * Hd;
    unsigned short* msgP   = msgAll + (size_t)N_A * Hd;
    int*            off    = (int*)(msgAll + (size_t)(N_A + N_P) * Hd);
    int2*           edges  = (int2*)(off + N_P);
    int*            bsum   = (int*)(edges + (E_W + E_C));
    float*          bc1    = (float*)(bsum + 256);
    float*          bcA2   = bc1 + 512;
    float*          bcP2   = bcA2 + 512;
    float*          bcP1   = bcP2 + 512;
    unsigned short* w1h    = (unsigned short*)(bcP1 + 512);
    unsigned short* w1l    = w1h  + (size_t)128 * 512;
    unsigned short* wA2h   = w1l  + (size_t)128 * 512;
    unsigned short* wA2l   = wA2h + (size_t)256 * 512;
    unsigned short* wP2h   = wA2l + (size_t)256 * 512;   // 256*512 shorts
    unsigned short* wP1h   = wP2h + (size_t)256 * 512;   // 512*512 shorts
    unsigned short* pfb    = (unsigned short*)
        (((uintptr_t)(wP1h + (size_t)512 * 512) + 63) & ~(uintptr_t)63);
    unsigned short* selfP  = pfb + (size_t)N_P * F_P;
    const size_t needPfb  = ((char*)(pfb  + (size_t)N_P * F_P)) - (char*)d_ws;
    const size_t needSelf = ((char*)(selfP + (size_t)N_P * Hd)) - (char*)d_ws;
    const bool usePfb  = (ws_size >= needPfb);
    const bool useSelf = (ws_size >= needSelf);

    const dim3 blk(256);
    const int  nb   = (N_P + 1023) / 1024;    // 98
    const int  gM   = (N_P + 127) / 128;      // 782
    const int  gPad = ((gM + 7) / 8) * 8 * 4; // 3136 (XCD-grouped, padded)

    // ---------------- prep ----------------
    prep_kernel<<<1184, 64, 0, stream>>>(W1sa, W1rw, W2sa, W2rw, W2rc, W2sp, W1sp, W1rc,
                                         b1sa, b1rw, b2sa, b2rw, b2rc, b2sp, b1sp, b1rc,
                                         w1h, w1l, wA2h, wA2l, wP2h, wP1h,
                                         bc1, bcA2, bcP2, bcP1);

    // ---------------- CSR build (+ fused pf conversion) ----------------
    hipMemsetAsync(off, 0, (size_t)N_P * sizeof(int), stream);
    if (usePfb) {
        convhist_kernel<<<2048, blk, 0, stream>>>(pf, pfb, (long)N_P * F_P / 4,
                                                  wdst, E_W, cdst, E_C, off);
    } else {
        hist_kernel<<<1024, blk, 0, stream>>>(wdst, E_W, cdst, E_C, off);
    }
    scan1_kernel<<<nb, blk, 0, stream>>>(off, N_P, bsum);
    scan2_kernel<<<1,  blk, 0, stream>>>(bsum, nb);
    scan3_kernel<<<(N_P + 255) / 256, blk, 0, stream>>>(off, N_P, bsum);
    fill_kernel<<<1024, blk, 0, stream>>>(wsrc, wdst, ww, E_W, csrc, cdst, cw, E_C,
                                          off, edges);

    // ---------------- Layer 1 ----------------
    if (usePfb) {
        mfma_tile2_kernel<1><<<gPad, blk, 32768, stream>>>(pfb, 512, 16, wP1h, bcP1,
                                                           xp1b, msgP, 1, 1, N_P, gM);
    } else {
        mfma_tile2_kernel<0><<<gPad, blk, 32768, stream>>>(pf, 512, 16, wP1h, bcP1,
                                                           xp1b, msgP, 1, 1, N_P, gM);
    }
    // author self (ELU, fp32 xa1) + writes msg (bf16 into msgAll)
    mfma_dual_kernel<<<N_A / 32, blk, 32 * 128 * 4, stream>>>(ae, 128, w1h, w1l, bc1,
                                                              xa1, msgAll, 1, 0, 0, 1);
    aggregate_kernel<1><<<N_P / 4, blk, 0, stream>>>(xp1b, nullptr, msgAll, off, edges, 1);

    // ---------------- Layer 2 ----------------
    mfma_dual_kernel<<<N_A / 32, blk, 32 * 256 * 4, stream>>>(xa1, 256, wA2h, wA2l, bcA2,
                                                              outA, msgAll, 0, 0, 0, 1);
    if (useSelf) {
        mfma_tile2_kernel<1><<<gPad, blk, 32768, stream>>>(xp1b, 256, 8, wP2h, bcP2,
                                                           msgP, selfP, 1, 1, N_P, gM);
        aggregate_kernel<2><<<N_P / 4, blk, 0, stream>>>(selfP, outP, msgAll, off, edges, 0);
    } else {
        mfma_tile2_kernel<1><<<gPad, blk, 32768, stream>>>(xp1b, 256, 8, wP2h, bcP2,
                                                           msgP, outP, 1, 0, N_P, gM);
        aggregate_kernel<0><<<N_P / 4, blk, 0, stream>>>(outP, nullptr, msgAll, off, edges, 0);
    }
}

// Round 19
// 444.427 us; speedup vs baseline: 1.0415x; 1.0415x over previous
//
#include <hip/hip_runtime.h>
#include <cstdint>
#include <cstddef>

constexpr int Hd  = 256;
constexpr int N_P = 100000;
constexpr int N_A = 20000;
constexpr int F_P = 512;
constexpr int D_A = 128;

typedef short bf16x8 __attribute__((ext_vector_type(8)));
typedef float f32x4  __attribute__((ext_vector_type(4)));

__device__ __forceinline__ unsigned short f2b(float x) {
    unsigned u = __float_as_uint(x);
    u += 0x7fffu + ((u >> 16) & 1u);
    return (unsigned short)(u >> 16);
}
__device__ __forceinline__ float b2f(unsigned short h) {
    return __uint_as_float((unsigned)h << 16);
}
__device__ __forceinline__ unsigned pk2(float lo, float hi) {
    return (__float_as_uint(lo) >> 16) | (__float_as_uint(hi) & 0xffff0000u);
}
__device__ __forceinline__ void bsplit(float x, unsigned short& hi, unsigned short& lo) {
    const unsigned u = __float_as_uint(x);
    hi = (unsigned short)(u >> 16);
    const float r = x - __uint_as_float(u & 0xffff0000u);
    lo = (unsigned short)(__float_as_uint(r) >> 16);
}

// async global->LDS, 16B per lane (m173 pre-swizzled-source pattern).
__device__ __forceinline__ void gld16(const void* g, void* l) {
    __builtin_amdgcn_global_load_lds(
        (const __attribute__((address_space(1))) unsigned int*)g,
        (__attribute__((address_space(3))) unsigned int*)l, 16, 0, 0);
}

// ---------------------------------------------------------------------------
// prep: pack W tables into MFMA B-fragment layout + bias concats. (proven)
// ---------------------------------------------------------------------------
__global__ void prep_kernel(const float* __restrict__ W1sa, const float* __restrict__ W1rw,
                            const float* __restrict__ W2sa, const float* __restrict__ W2rw,
                            const float* __restrict__ W2rc, const float* __restrict__ W2sp,
                            const float* __restrict__ W1sp, const float* __restrict__ W1rc,
                            const float* __restrict__ b1sa, const float* __restrict__ b1rw,
                            const float* __restrict__ b2sa, const float* __restrict__ b2rw,
                            const float* __restrict__ b2rc, const float* __restrict__ b2sp,
                            const float* __restrict__ b1sp, const float* __restrict__ b1rc,
                            unsigned short* __restrict__ w1h,  unsigned short* __restrict__ w1l,
                            unsigned short* __restrict__ wA2h, unsigned short* __restrict__ wA2l,
                            unsigned short* __restrict__ wP2h,
                            unsigned short* __restrict__ wP1h,
                            float* __restrict__ bc1, float* __restrict__ bcA2,
                            float* __restrict__ bcP2, float* __restrict__ bcP1) {
    const int b = blockIdx.x;
    const int l = threadIdx.x;
    if (b < 384) {
        const float *Wa, *Wb; unsigned short *wh, *wl; int rel;
        if (b < 128) { Wa = W1sa; Wb = W1rw; wh = w1h;  wl = w1l;  rel = b; }
        else         { Wa = W2sa; Wb = W2rw; wh = wA2h; wl = wA2l; rel = b - 128; }
        const int ks  = rel >> 5;
        const int nfg = rel & 31;
        const float* W = (nfg < 16) ? Wa : Wb;
        const int col  = (nfg & 15) * 16 + (l & 15);
        const size_t base = ((size_t)rel * 64 + l) * 8;
        #pragma unroll
        for (int j = 0; j < 8; ++j) {
            const int k = ks * 32 + ((l >> 4) * 8) + j;
            unsigned short h, lw;
            bsplit(W[(size_t)k * Hd + col], h, lw);
            wh[base + j] = h;
            wl[base + j] = lw;
        }
    } else if (b < 640) {
        const int rel = b - 384;                  // [0,256)
        const int ks  = rel >> 5;
        const int nfg = rel & 31;
        const float* W = (nfg < 16) ? W2rc : W2sp;
        const int col  = (nfg & 15) * 16 + (l & 15);
        const size_t base = ((size_t)rel * 64 + l) * 8;
        #pragma unroll
        for (int j = 0; j < 8; ++j) {
            const int k = ks * 32 + ((l >> 4) * 8) + j;
            wP2h[base + j] = f2b(W[(size_t)k * Hd + col]);
        }
    } else if (b < 1152) {
        const int rel = b - 640;                  // [0,512)
        const int ks  = rel >> 5;
        const int nfg = rel & 31;
        const float* W = (nfg < 16) ? W1sp : W1rc;
        const int col  = (nfg & 15) * 16 + (l & 15);
        const size_t base = ((size_t)rel * 64 + l) * 8;
        #pragma unroll
        for (int j = 0; j < 8; ++j) {
            const int k = ks * 32 + ((l >> 4) * 8) + j;
            wP1h[base + j] = f2b(W[(size_t)k * Hd + col]);
        }
    } else {
        const int t     = (b - 1152) * 64 + l;    // 0..2047
        const int which = t >> 9;
        const int idx   = t & 511;
        const float* src; float* dst;
        if (which == 0)      { src = (idx < 256) ? b1sa : b1rw; dst = bc1;  }
        else if (which == 1) { src = (idx < 256) ? b2sa : b2rw; dst = bcA2; }
        else if (which == 2) { src = (idx < 256) ? b2rc : b2sp; dst = bcP2; }
        else                 { src = (idx < 256) ? b1sp : b1rc; dst = bcP1; }
        dst[idx] = src[idx & 255];
    }
}

// ---------------------------------------------------------------------------
// Fused conv + hist (proven neutral-or-better; keeps one launch less).
// ---------------------------------------------------------------------------
__global__ void convhist_kernel(const float* __restrict__ in, unsigned short* __restrict__ out,
                                const long n4,
                                const int* __restrict__ wdst, const int EW,
                                const int* __restrict__ cdst, const int EC,
                                int* __restrict__ cnt) {
    const int b = blockIdx.x;
    if (b < 1024) {
        const long stride = (long)1024 * blockDim.x;
        for (long i = (long)b * blockDim.x + threadIdx.x; i < n4; i += stride) {
            const float4 v = ((const float4*)in)[i];
            ((ushort4*)out)[i] = make_ushort4(
                (unsigned short)(__float_as_uint(v.x) >> 16),
                (unsigned short)(__float_as_uint(v.y) >> 16),
                (unsigned short)(__float_as_uint(v.z) >> 16),
                (unsigned short)(__float_as_uint(v.w) >> 16));
        }
    } else {
        const int stride = 1024 * blockDim.x;
        for (int i = (b - 1024) * blockDim.x + threadIdx.x; i < EW + EC; i += stride) {
            const int d = (i < EW) ? wdst[i] : cdst[i - EW];
            atomicAdd(&cnt[d], 1);
        }
    }
}

// standalone hist (fallback path without pfb)
__global__ void hist_kernel(const int* __restrict__ wdst, const int EW,
                            const int* __restrict__ cdst, const int EC,
                            int* __restrict__ cnt) {
    for (int i = blockIdx.x * blockDim.x + threadIdx.x; i < EW + EC; i += gridDim.x * blockDim.x) {
        const int d = (i < EW) ? wdst[i] : cdst[i - EW];
        atomicAdd(&cnt[d], 1);
    }
}

// ---------------------------------------------------------------------------
// TILE2 MFMA GEMM (proven R17): 128x128 tile, BK=32, 4 waves, gld16 staging,
// XCD-grouped block mapping.
// ---------------------------------------------------------------------------
template<int AMODE>
__global__ void __launch_bounds__(256, 3)
mfma_tile2_kernel(const void* __restrict__ Av, const int KA, const int nks,
                  const unsigned short* __restrict__ wtab,
                  const float* __restrict__ bcat,
                  void* __restrict__ Oa, void* __restrict__ Ob,
                  const int bfA, const int bfB, const int Mtot, const int gM) {
    const int d = blockIdx.x;
    const int r = ((d >> 5) << 3) + (d & 7);
    if (r >= gM) return;
    const int c = (d >> 3) & 3;

    extern __shared__ char smem[];                 // [2][ A:8KB | B:8KB ]
    const int tid = threadIdx.x;
    const int wid = tid >> 6;
    const int l   = tid & 63;
    const long m0 = (long)r * 128;
    const int wr  = wid >> 1, wc = wid & 1;

    const unsigned short* bg0 = wtab + ((size_t)(c * 8 + 2 * wid) * 512) + l * 8;
    const unsigned short* bg1 = bg0 + 512;

    const unsigned short* ag0 = nullptr; const unsigned short* ag1 = nullptr;
    const float* Af = nullptr;
    long grow0 = 0, grow1 = 0; int kg = 0;
    if constexpr (AMODE == 1) {
        const unsigned short* A = (const unsigned short*)Av;
        long r0 = m0 + (2 * wid) * 16 + (l & 15);     if (r0 > Mtot - 1) r0 = Mtot - 1;
        long r1 = m0 + (2 * wid + 1) * 16 + (l & 15); if (r1 > Mtot - 1) r1 = Mtot - 1;
        ag0 = A + r0 * KA + ((l >> 4) * 8);
        ag1 = A + r1 * KA + ((l >> 4) * 8);
    } else {
        Af = (const float*)Av;
        const int f0 = tid >> 6;
        grow0 = m0 + f0 * 16 + (l & 15);       if (grow0 > Mtot - 1) grow0 = Mtot - 1;
        grow1 = m0 + (f0 + 4) * 16 + (l & 15); if (grow1 > Mtot - 1) grow1 = Mtot - 1;
        kg = (l >> 4) * 8;
    }

    float4 a00, a01, a10, a11;

#define STAGE_B(BUF, KS) { \
    char* Bb_ = smem + (BUF) * 16384 + 8192; \
    gld16(bg0 + (size_t)(KS) * 16384, Bb_ + wid * 2048); \
    gld16(bg1 + (size_t)(KS) * 16384, Bb_ + wid * 2048 + 1024); }
#define STAGE_A1(BUF, KS) { \
    char* Ab_ = smem + (BUF) * 16384; \
    gld16(ag0 + (KS) * 32, Ab_ + wid * 2048); \
    gld16(ag1 + (KS) * 32, Ab_ + wid * 2048 + 1024); }
#define LOAD_A0(KS) { \
    const float* p0_ = Af + grow0 * KA + (KS) * 32 + kg; \
    const float* p1_ = Af + grow1 * KA + (KS) * 32 + kg; \
    a00 = *(const float4*)p0_; a01 = *(const float4*)(p0_ + 4); \
    a10 = *(const float4*)p1_; a11 = *(const float4*)(p1_ + 4); }
#define WRITE_A0(BUF) { \
    char* Ab_ = smem + (BUF) * 16384; \
    *(uint4*)(Ab_ + tid * 16) = make_uint4(pk2(a00.x, a00.y), pk2(a00.z, a00.w), \
                                           pk2(a01.x, a01.y), pk2(a01.z, a01.w)); \
    *(uint4*)(Ab_ + (tid + 256) * 16) = make_uint4(pk2(a10.x, a10.y), pk2(a10.z, a10.w), \
                                                   pk2(a11.x, a11.y), pk2(a11.z, a11.w)); }

    f32x4 acc[4][4];
    #pragma unroll
    for (int nf = 0; nf < 4; ++nf) {
        const float b = bcat[c * 128 + wc * 64 + nf * 16 + (l & 15)];
        #pragma unroll
        for (int mf = 0; mf < 4; ++mf) acc[mf][nf] = (f32x4){b, b, b, b};
    }

    STAGE_B(0, 0)
    if constexpr (AMODE == 1) { STAGE_A1(0, 0) }
    else { LOAD_A0(0) WRITE_A0(0) }
    __syncthreads();

    int cur = 0;
    for (int ks = 0; ks < nks; ++ks) {
        const bool more = (ks + 1 < nks);
        if (more) {
            STAGE_B(cur ^ 1, ks + 1)
            if constexpr (AMODE == 1) { STAGE_A1(cur ^ 1, ks + 1) }
            else { LOAD_A0(ks + 1) }
        }
        {
            const char* Ab = smem + cur * 16384;
            const char* Bb = Ab + 8192;
            bf16x8 af[4], bfv[4];
            #pragma unroll
            for (int mf = 0; mf < 4; ++mf)
                af[mf] = *(const bf16x8*)(Ab + ((wr * 4 + mf) * 64 + l) * 16);
            #pragma unroll
            for (int nf = 0; nf < 4; ++nf)
                bfv[nf] = *(const bf16x8*)(Bb + ((wc * 4 + nf) * 64 + l) * 16);
            #pragma unroll
            for (int nf = 0; nf < 4; ++nf) {
                #pragma unroll
                for (int mf = 0; mf < 4; ++mf)
                    acc[mf][nf] = __builtin_amdgcn_mfma_f32_16x16x32_bf16(af[mf], bfv[nf], acc[mf][nf], 0, 0, 0);
            }
        }
        if (more) { if constexpr (AMODE == 0) WRITE_A0(cur ^ 1) }
        __syncthreads();
        cur ^= 1;
    }
#undef STAGE_B
#undef STAGE_A1
#undef LOAD_A0
#undef WRITE_A0

    #pragma unroll
    for (int mf = 0; mf < 4; ++mf) {
        #pragma unroll
        for (int nf = 0; nf < 4; ++nf) {
            const int gcol = c * 128 + wc * 64 + nf * 16 + (l & 15);
            void* O; int col, isbf;
            if (gcol < 256) { O = Oa; col = gcol;       isbf = bfA; }
            else            { O = Ob; col = gcol - 256; isbf = bfB; }
            const long row = m0 + wr * 64 + mf * 16 + ((l >> 4) * 4);
            const f32x4 v = acc[mf][nf];
            #pragma unroll
            for (int rr = 0; rr < 4; ++rr) {
                if (row + rr < Mtot) {
                    const float x = v[rr];
                    if (isbf) ((unsigned short*)O)[(row + rr) * Hd + col] = f2b(x);
                    else      ((float*)O)[(row + rr) * Hd + col] = x;
                }
            }
        }
    }
}

// ---------------------------------------------------------------------------
// Dual-output MFMA GEMM (author GEMMs only): fp32 A, split-bf16 3-product.
// ---------------------------------------------------------------------------
__global__ void mfma_dual_kernel(const void* __restrict__ Av, const int K,
                                 const unsigned short* __restrict__ whi,
                                 const unsigned short* __restrict__ wlo,
                                 const float* __restrict__ bcat,
                                 void* __restrict__ Oa, void* __restrict__ Ob,
                                 const int actA, const int actB,
                                 const int bfA, const int bfB) {
    extern __shared__ char smem[];
    char* sh = smem;
    char* sl = smem + 32 * K * 2;
    const int  tid = threadIdx.x;
    const int  wid = tid >> 6;
    const int  l   = tid & 63;
    const long m0  = (long)blockIdx.x * 32;
    const int  rowStride = 2 * K;

    const int kq4 = K >> 2;
    const float* A = (const float*)Av;
    for (int i = tid; i < 32 * kq4; i += 256) {
        const int row = i / kq4;
        const int kq  = i - row * kq4;
        const float4 v = *(const float4*)(A + (m0 + row) * K + kq * 4);
        unsigned short h0, h1, h2, h3, l0, l1, l2, l3;
        bsplit(v.x, h0, l0); bsplit(v.y, h1, l1);
        bsplit(v.z, h2, l2); bsplit(v.w, h3, l3);
        const int ofs = row * rowStride + ((kq * 8) ^ ((row & 7) << 4));
        *(ushort4*)(sh + ofs) = make_ushort4(h0, h1, h2, h3);
        *(ushort4*)(sl + ofs) = make_ushort4(l0, l1, l2, l3);
    }
    __syncthreads();

    f32x4 acc[2][8];
    #pragma unroll
    for (int nf = 0; nf < 8; ++nf) {
        const float b = bcat[wid * 128 + nf * 16 + (l & 15)];
        acc[0][nf] = (f32x4){b, b, b, b};
        acc[1][nf] = (f32x4){b, b, b, b};
    }

    const int kb  = (l >> 4) * 16;
    const int r0  = l & 15;
    const int r1  = 16 + r0;
    const int sw  = (l & 7) << 4;
    const int ro0 = r0 * rowStride;
    const int ro1 = r1 * rowStride;
    for (int ks = 0; ks < (K >> 5); ++ks) {
        const int bk = (ks * 64 + kb) ^ sw;
        const bf16x8 ah0 = *(const bf16x8*)(sh + ro0 + bk);
        const bf16x8 ah1 = *(const bf16x8*)(sh + ro1 + bk);
        const bf16x8 al0 = *(const bf16x8*)(sl + ro0 + bk);
        const bf16x8 al1 = *(const bf16x8*)(sl + ro1 + bk);
        const size_t wbase = (((size_t)ks * 32 + wid * 8) * 64 + l) * 8;
        #pragma unroll
        for (int nf = 0; nf < 8; ++nf) {
            const bf16x8 bh = *(const bf16x8*)(whi + wbase + (size_t)nf * 512);
            const bf16x8 bl = *(const bf16x8*)(wlo + wbase + (size_t)nf * 512);
            acc[0][nf] = __builtin_amdgcn_mfma_f32_16x16x32_bf16(ah0, bh, acc[0][nf], 0, 0, 0);
            acc[1][nf] = __builtin_amdgcn_mfma_f32_16x16x32_bf16(ah1, bh, acc[1][nf], 0, 0, 0);
            acc[0][nf] = __builtin_amdgcn_mfma_f32_16x16x32_bf16(al0, bh, acc[0][nf], 0, 0, 0);
            acc[1][nf] = __builtin_amdgcn_mfma_f32_16x16x32_bf16(al1, bh, acc[1][nf], 0, 0, 0);
            acc[0][nf] = __builtin_amdgcn_mfma_f32_16x16x32_bf16(ah0, bl, acc[0][nf], 0, 0, 0);
            acc[1][nf] = __builtin_amdgcn_mfma_f32_16x16x32_bf16(ah1, bl, acc[1][nf], 0, 0, 0);
        }
    }

    #pragma unroll
    for (int mf = 0; mf < 2; ++mf) {
        #pragma unroll
        for (int nf = 0; nf < 8; ++nf) {
            const int colg = wid * 128 + nf * 16 + (l & 15);
            void* O;
            int col, act, isbf;
            if (colg < 256) { O = Oa; col = colg;       act = actA; isbf = bfA; }
            else            { O = Ob; col = colg - 256; act = actB; isbf = bfB; }
            const long row = m0 + mf * 16 + ((l >> 4) * 4);
            const f32x4 v = acc[mf][nf];
            #pragma unroll
            for (int r = 0; r < 4; ++r) {
                float x = v[r];
                if (act) x = x > 0.f ? x : expm1f(x);
                if (isbf) ((unsigned short*)O)[(row + r) * Hd + col] = f2b(x);
                else      ((float*)O)[(row + r) * Hd + col] = x;
            }
        }
    }
}

// ---------------------------------------------------------------------------
// CSR scans + fill. (proven)
// ---------------------------------------------------------------------------
__global__ void scan1_kernel(int* __restrict__ data, const int n, int* __restrict__ bsum) {
    __shared__ int s[256];
    const int t = threadIdx.x;
    const int base = blockIdx.x * 1024 + t * 4;
    int v0 = (base + 0 < n) ? data[base + 0] : 0;
    int v1 = (base + 1 < n) ? data[base + 1] : 0;
    int v2 = (base + 2 < n) ? data[base + 2] : 0;
    int v3 = (base + 3 < n) ? data[base + 3] : 0;
    const int tsum = v0 + v1 + v2 + v3;
    s[t] = tsum;
    __syncthreads();
    for (int off = 1; off < 256; off <<= 1) {
        int y = (t >= off) ? s[t - off] : 0;
        __syncthreads();
        if (t >= off) s[t] += y;
        __syncthreads();
    }
    const int e = s[t] - tsum;
    if (base + 0 < n) data[base + 0] = e;
    if (base + 1 < n) data[base + 1] = e + v0;
    if (base + 2 < n) data[base + 2] = e + v0 + v1;
    if (base + 3 < n) data[base + 3] = e + v0 + v1 + v2;
    if (t == 255) bsum[blockIdx.x] = s[255];
}

__global__ void scan2_kernel(int* __restrict__ bsum, const int nb) {
    __shared__ int s[256];
    const int t = threadIdx.x;
    const int v = (t < nb) ? bsum[t] : 0;
    s[t] = v;
    __syncthreads();
    for (int off = 1; off < 256; off <<= 1) {
        int y = (t >= off) ? s[t - off] : 0;
        __syncthreads();
        if (t >= off) s[t] += y;
        __syncthreads();
    }
    if (t < nb) bsum[t] = s[t] - v;
}

__global__ void scan3_kernel(int* __restrict__ data, const int n, const int* __restrict__ bsum) {
    const int i = blockIdx.x * blockDim.x + threadIdx.x;
    if (i < n) data[i] += bsum[i >> 10];
}

__global__ void fill_kernel(const int* __restrict__ wsrc, const int* __restrict__ wdst,
                            const float* __restrict__ ww, const int EW,
                            const int* __restrict__ csrc, const int* __restrict__ cdst,
                            const float* __restrict__ cw, const int EC,
                            int* __restrict__ cur, int2* __restrict__ edges) {
    for (int i = blockIdx.x * blockDim.x + threadIdx.x; i < EW + EC; i += gridDim.x * blockDim.x) {
        int d, sp; float w;
        if (i < EW) { d = wdst[i]; sp = wsrc[i]; w = ww[i]; }
        else        { const int j = i - EW; d = cdst[j]; sp = N_A + csrc[j]; w = cw[j]; }
        const int p = atomicAdd(&cur[d], 1);
        edges[p] = make_int2(sp, __float_as_int(w));
    }
}

// ---------------------------------------------------------------------------
// Pull aggregation: proven skeleton, EXACT-TAIL depth-2 ping-pong
// (nc = ceil(n/4), no even-forcing, no min-2 -> minimal wasted gather slots;
// avg degree is only ~6 so slot waste dominated the old variants).
// MODE 0: fp32 in-place. MODE 1: bf16 in-place (+ELU).
// MODE 2: read bf16 self from iov, write fp32 to outv.
// ---------------------------------------------------------------------------
struct AgChunk { ushort4 g0, g1, g2, g3; float w0, w1, w2, w3; };

__device__ __forceinline__ void ag_issue(const int2* __restrict__ eq, const int base, const int n,
                                         const unsigned short* __restrict__ msg,
                                         const int lane, AgChunk& C) {
#define AG_ONE(J, GG, WW) { \
    const int idx = base + (J); \
    const int2 ee = eq[min(idx, n - 1)]; \
    WW = (idx < n) ? __int_as_float(ee.y) : 0.f; \
    GG = ((const ushort4*)(msg + (size_t)ee.x * Hd))[lane]; }
    AG_ONE(0, C.g0, C.w0)
    AG_ONE(1, C.g1, C.w1)
    AG_ONE(2, C.g2, C.w2)
    AG_ONE(3, C.g3, C.w3)
#undef AG_ONE
}

__device__ __forceinline__ void ag_acc(const AgChunk& C, float4& acc) {
#define AG_A(GG, WW) { \
    acc.x = fmaf(WW, b2f(GG.x), acc.x); acc.y = fmaf(WW, b2f(GG.y), acc.y); \
    acc.z = fmaf(WW, b2f(GG.z), acc.z); acc.w = fmaf(WW, b2f(GG.w), acc.w); }
    AG_A(C.g0, C.w0) AG_A(C.g1, C.w1) AG_A(C.g2, C.w2) AG_A(C.g3, C.w3)
#undef AG_A
}

template<int MODE>
__global__ void aggregate_kernel(void* __restrict__ iov, void* __restrict__ outv,
                                 const unsigned short* __restrict__ msgAll,
                                 const int* __restrict__ off,
                                 const int2* __restrict__ edges,
                                 const int do_elu) {
    __shared__ int2 eq[1024];
    const int wid  = threadIdx.x >> 6;
    const int lane = threadIdx.x & 63;
    const int p0   = blockIdx.x * 4;
    const int sAll = (p0 == 0) ? 0 : off[p0 - 1];
    const int tot  = off[p0 + 3] - sAll;
    const bool fits = (tot <= 1024);
    if (fits)
        for (int i = threadIdx.x; i < tot; i += 256) eq[i] = edges[sAll + i];
    __syncthreads();

    const int p = p0 + wid;
    const int s = (p == 0) ? 0 : off[p - 1];
    const int e = off[p];
    const int n = e - s;

    float4 acc;
    if constexpr (MODE >= 1) {
        const ushort4 t = ((const ushort4*)((const unsigned short*)iov + (size_t)p * Hd))[lane];
        acc = make_float4(b2f(t.x), b2f(t.y), b2f(t.z), b2f(t.w));
    } else {
        acc = ((const float4*)((const float*)iov + (size_t)p * Hd))[lane];
    }

    if (n > 0) {
        if (fits) {
            const int2* eqw = eq + (s - sAll);
            const int nc = (n + 3) >> 2;           // exact chunk count, >= 1
            AgChunk CA, CB;
            ag_issue(eqw, 0, n, msgAll, lane, CA);
            if (nc > 1) ag_issue(eqw, 4, n, msgAll, lane, CB);
            int c = 0;
            for (; c + 2 < nc; c += 2) {
                ag_acc(CA, acc);
                ag_issue(eqw, 4 * (c + 2), n, msgAll, lane, CA);
                ag_acc(CB, acc);
                if (c + 3 < nc) ag_issue(eqw, 4 * (c + 3), n, msgAll, lane, CB);
            }
            // remaining chunks: c .. nc-1 live in CA (and CB if two remain)
            ag_acc(CA, acc);
            if (nc - c == 2) ag_acc(CB, acc);
        } else {
            for (int i = s; i < e; ++i) {
                const int2 ee = edges[i];
                const ushort4 g = ((const ushort4*)(msgAll + (size_t)ee.x * Hd))[lane];
                const float w = __int_as_float(ee.y);
                acc.x = fmaf(w, b2f(g.x), acc.x); acc.y = fmaf(w, b2f(g.y), acc.y);
                acc.z = fmaf(w, b2f(g.z), acc.z); acc.w = fmaf(w, b2f(g.w), acc.w);
            }
        }
    }
    if (do_elu) {
        acc.x = acc.x > 0.f ? acc.x : expm1f(acc.x);
        acc.y = acc.y > 0.f ? acc.y : expm1f(acc.y);
        acc.z = acc.z > 0.f ? acc.z : expm1f(acc.z);
        acc.w = acc.w > 0.f ? acc.w : expm1f(acc.w);
    }
    if constexpr (MODE == 1) {
        ((ushort4*)((unsigned short*)iov + (size_t)p * Hd))[lane] =
            make_ushort4(f2b(acc.x), f2b(acc.y), f2b(acc.z), f2b(acc.w));
    } else if constexpr (MODE == 2) {
        ((float4*)((float*)outv + (size_t)p * Hd))[lane] = acc;
    } else {
        ((float4*)((float*)iov + (size_t)p * Hd))[lane] = acc;
    }
}

extern "C" void kernel_launch(void* const* d_in, const int* in_sizes, int n_in,
                              void* d_out, int out_size, void* d_ws, size_t ws_size,
                              hipStream_t stream) {
    const float* pf    = (const float*)d_in[0];
    const float* ae    = (const float*)d_in[1];
    const int*   wsrc  = (const int*)d_in[2];
    const int*   wdst  = (const int*)d_in[3];
    const float* ww    = (const float*)d_in[4];
    const int*   csrc  = (const int*)d_in[5];
    const int*   cdst  = (const int*)d_in[6];
    const float* cw    = (const float*)d_in[7];
    const float* W1sp  = (const float*)d_in[8];
    const float* b1sp  = (const float*)d_in[9];
    const float* W1sa  = (const float*)d_in[10];
    const float* b1sa  = (const float*)d_in[11];
    const float* W1rw  = (const float*)d_in[12];
    const float* b1rw  = (const float*)d_in[13];
    const float* W1rc  = (const float*)d_in[14];
    const float* b1rc  = (const float*)d_in[15];
    const float* W2sp  = (const float*)d_in[16];
    const float* b2sp  = (const float*)d_in[17];
    const float* W2sa  = (const float*)d_in[18];
    const float* b2sa  = (const float*)d_in[19];
    const float* W2rw  = (const float*)d_in[20];
    const float* b2rw  = (const float*)d_in[21];
    const float* W2rc  = (const float*)d_in[22];
    const float* b2rc  = (const float*)d_in[23];

    const int E_W = in_sizes[2];
    const int E_C = in_sizes[5];

    float* outP = (float*)d_out;                        // [N_P, 256] fp32
    float* outA = outP + (size_t)N_P * Hd;              // [N_A, 256] fp32

    // Workspace layout (R17):
    float*          xa1    = (float*)d_ws;
    unsigned short* xp1b   = (unsigned short*)(xa1 + (size_t)N_A * Hd);
    unsigned short* msgAll = xp1b + (size_t)N_P * Hd;
    unsigned short* msgP   = msgAll + (size_t)N_A * Hd;
    int*            off    = (int*)(msgAll + (size_t)(N_A + N_P) * Hd);
    int2*           edges  = (int2*)(off + N_P);
    int*            bsum   = (int*)(edges + (E_W + E_C));
    float*          bc1    = (float*)(bsum + 256);
    float*          bcA2   = bc1 + 512;
    float*          bcP2   = bcA2 + 512;
    float*          bcP1   = bcP2 + 512;
    unsigned short* w1h    = (unsigned short*)(bcP1 + 512);
    unsigned short* w1l    = w1h  + (size_t)128 * 512;
    unsigned short* wA2h   = w1l  + (size_t)128 * 512;
    unsigned short* wA2l   = wA2h + (size_t)256 * 512;
    unsigned short* wP2h   = wA2l + (size_t)256 * 512;   // 256*512 shorts
    unsigned short* wP1h   = wP2h + (size_t)256 * 512;   // 512*512 shorts
    unsigned short* pfb    = (unsigned short*)
        (((uintptr_t)(wP1h + (size_t)512 * 512) + 63) & ~(uintptr_t)63);
    unsigned short* selfP  = pfb + (size_t)N_P * F_P;
    const size_t needPfb  = ((char*)(pfb  + (size_t)N_P * F_P)) - (char*)d_ws;
    const size_t needSelf = ((char*)(selfP + (size_t)N_P * Hd)) - (char*)d_ws;
    const bool usePfb  = (ws_size >= needPfb);
    const bool useSelf = (ws_size >= needSelf);

    const dim3 blk(256);
    const int  nb   = (N_P + 1023) / 1024;    // 98
    const int  gM   = (N_P + 127) / 128;      // 782
    const int  gPad = ((gM + 7) / 8) * 8 * 4; // 3136 (XCD-grouped, padded)

    // ---------------- prep ----------------
    prep_kernel<<<1184, 64, 0, stream>>>(W1sa, W1rw, W2sa, W2rw, W2rc, W2sp, W1sp, W1rc,
                                         b1sa, b1rw, b2sa, b2rw, b2rc, b2sp, b1sp, b1rc,
                                         w1h, w1l, wA2h, wA2l, wP2h, wP1h,
                                         bc1, bcA2, bcP2, bcP1);

    // ---------------- CSR build (+ fused pf conversion) ----------------
    hipMemsetAsync(off, 0, (size_t)N_P * sizeof(int), stream);
    if (usePfb) {
        convhist_kernel<<<2048, blk, 0, stream>>>(pf, pfb, (long)N_P * F_P / 4,
                                                  wdst, E_W, cdst, E_C, off);
    } else {
        hist_kernel<<<1024, blk, 0, stream>>>(wdst, E_W, cdst, E_C, off);
    }
    scan1_kernel<<<nb, blk, 0, stream>>>(off, N_P, bsum);
    scan2_kernel<<<1,  blk, 0, stream>>>(bsum, nb);
    scan3_kernel<<<(N_P + 255) / 256, blk, 0, stream>>>(off, N_P, bsum);
    fill_kernel<<<1024, blk, 0, stream>>>(wsrc, wdst, ww, E_W, csrc, cdst, cw, E_C,
                                          off, edges);

    // ---------------- Layer 1 ----------------
    if (usePfb) {
        mfma_tile2_kernel<1><<<gPad, blk, 32768, stream>>>(pfb, 512, 16, wP1h, bcP1,
                                                           xp1b, msgP, 1, 1, N_P, gM);
    } else {
        mfma_tile2_kernel<0><<<gPad, blk, 32768, stream>>>(pf, 512, 16, wP1h, bcP1,
                                                           xp1b, msgP, 1, 1, N_P, gM);
    }
    // author self (ELU, fp32 xa1) + writes msg (bf16 into msgAll)
    mfma_dual_kernel<<<N_A / 32, blk, 32 * 128 * 4, stream>>>(ae, 128, w1h, w1l, bc1,
                                                              xa1, msgAll, 1, 0, 0, 1);
    aggregate_kernel<1><<<N_P / 4, blk, 0, stream>>>(xp1b, nullptr, msgAll, off, edges, 1);

    // ---------------- Layer 2 ----------------
    mfma_dual_kernel<<<N_A / 32, blk, 32 * 256 * 4, stream>>>(xa1, 256, wA2h, wA2l, bcA2,
                                                              outA, msgAll, 0, 0, 0, 1);
    if (useSelf) {
        mfma_tile2_kernel<1><<<gPad, blk, 32768, stream>>>(xp1b, 256, 8, wP2h, bcP2,
                                                           msgP, selfP, 1, 1, N_P, gM);
        aggregate_kernel<2><<<N_P / 4, blk, 0, stream>>>(selfP, outP, msgAll, off, edges, 0);
    } else {
        mfma_tile2_kernel<1><<<gPad, blk, 32768, stream>>>(xp1b, 256, 8, wP2h, bcP2,
                                                           msgP, outP, 1, 0, N_P, gM);
        aggregate_kernel<0><<<N_P / 4, blk, 0, stream>>>(outP, nullptr, msgAll, off, edges, 0);
    }
}